// Round 1
// baseline (187.464 us; speedup 1.0000x reference)
//
#include <hip/hip_runtime.h>

typedef unsigned short ushort_t;
typedef short bf16x8 __attribute__((ext_vector_type(8)));
typedef float f32x4 __attribute__((ext_vector_type(4)));

#define B_ 8
#define L_ 512
#define D_ 1024
#define H_ 16
#define HD_ 64
#define M_ 4096
#define N_ 1024
#define K_ 1024

__device__ __forceinline__ ushort_t f2bf(float f) {
  union { float f; unsigned u; } v; v.f = f;
  unsigned r = v.u + 0x7FFFu + ((v.u >> 16) & 1u);
  return (ushort_t)(r >> 16);
}
__device__ __forceinline__ float bf2f(ushort_t h) {
  union { unsigned u; float f; } v; v.u = ((unsigned)h) << 16;
  return v.f;
}

// ---------------- RoPE cos/sin table: [512][32] ----------------
__global__ __launch_bounds__(256) void rope_table_kernel(float* __restrict__ cosb,
                                                         float* __restrict__ sinb) {
  int idx = blockIdx.x * 256 + threadIdx.x;
  if (idx >= L_ * 32) return;
  int l = idx >> 5, i = idx & 31;
  float inv = powf(10000.0f, (-2.0f * (float)i) / 1024.0f);
  float ang = (float)l * inv;
  cosb[idx] = cosf(ang);
  sinb[idx] = sinf(ang);
}

// ---------------- LayerNorm (fp32 in -> bf16 out) ----------------
__global__ __launch_bounds__(256) void ln_kernel(const float* __restrict__ x,
                                                 const float* __restrict__ g,
                                                 const float* __restrict__ b,
                                                 ushort_t* __restrict__ xn) {
  int row = blockIdx.x, t = threadIdx.x;
  float4 v = ((const float4*)(x + (size_t)row * D_))[t];
  float s  = v.x + v.y + v.z + v.w;
  float s2 = v.x * v.x + v.y * v.y + v.z * v.z + v.w * v.w;
#pragma unroll
  for (int m = 1; m < 64; m <<= 1) { s += __shfl_xor(s, m); s2 += __shfl_xor(s2, m); }
  __shared__ float red[8];
  int w = t >> 6;
  if ((t & 63) == 0) { red[w] = s; red[4 + w] = s2; }
  __syncthreads();
  s  = red[0] + red[1] + red[2] + red[3];
  s2 = red[4] + red[5] + red[6] + red[7];
  float mean = s * (1.0f / D_);
  float var  = s2 * (1.0f / D_) - mean * mean;
  float rs   = rsqrtf(var + 1e-5f);
  float4 gg = ((const float4*)g)[t];
  float4 bb = ((const float4*)b)[t];
  unsigned long long pk =
      (unsigned long long)f2bf((v.x - mean) * rs * gg.x + bb.x)
    | ((unsigned long long)f2bf((v.y - mean) * rs * gg.y + bb.y) << 16)
    | ((unsigned long long)f2bf((v.z - mean) * rs * gg.z + bb.z) << 32)
    | ((unsigned long long)f2bf((v.w - mean) * rs * gg.w + bb.w) << 48);
  *(unsigned long long*)(xn + (size_t)row * D_ + t * 4) = pk;
}

// ---------------- Weight transpose + fp32->bf16: WT[n][k] = W[k][n] ----------------
__global__ __launch_bounds__(256) void wtrans_kernel(const float* __restrict__ w0,
                                                     const float* __restrict__ w1,
                                                     const float* __restrict__ w2,
                                                     const float* __restrict__ w3,
                                                     ushort_t* __restrict__ wt) {
  const float* W = (blockIdx.z == 0) ? w0 : (blockIdx.z == 1) ? w1
                 : (blockIdx.z == 2) ? w2 : w3;
  ushort_t* WT = wt + (size_t)blockIdx.z * 1024 * 1024;
  __shared__ float tile[32][33];
  int tx = threadIdx.x, ty = threadIdx.y;  // 32 x 8
  int k0 = blockIdx.y * 32, n0 = blockIdx.x * 32;
#pragma unroll
  for (int j = 0; j < 4; ++j)
    tile[ty + 8 * j][tx] = W[(size_t)(k0 + ty + 8 * j) * 1024 + n0 + tx];
  __syncthreads();
#pragma unroll
  for (int j = 0; j < 4; ++j)
    WT[(size_t)(n0 + ty + 8 * j) * 1024 + k0 + tx] = f2bf(tile[tx][ty + 8 * j]);
}

// ---------------- GEMM: C[m][n] = sum_k A[m][k] * Bt[n][k]  (+bias, +res) ----------------
// A [M,K] bf16 row-major, Bt [N,K] bf16 row-major. 128x128 tile, BK=64, 4 waves.
// OUTMODE 0: bf16 out.  OUTMODE 1: fp32 out = acc + bias + res.
template <int OUTMODE>
__global__ __launch_bounds__(256) void gemm_bt(const ushort_t* __restrict__ A,
                                               const ushort_t* __restrict__ Bt,
                                               const float* __restrict__ bias,
                                               const float* __restrict__ res,
                                               void* __restrict__ Cout) {
  __shared__ ushort_t As[128 * 64];
  __shared__ ushort_t Bs[128 * 64];
  int t = threadIdx.x;
  int l = t & 63, w = t >> 6;
  int wr = w >> 1, wc = w & 1;
  int lr = l & 15, lg = l >> 4;
  int m0 = blockIdx.y * 128, n0 = blockIdx.x * 128;

  f32x4 acc[4][4] = {};

  for (int k0 = 0; k0 < K_; k0 += 64) {
    // stage A,B tiles: each thread 4x(8 bf16) per matrix; XOR slot swizzle on 16B slots
#pragma unroll
    for (int it = 0; it < 4; ++it) {
      int idx = it * 2048 + t * 8;
      int row = idx >> 6, col = idx & 63;
      int sslot = ((col >> 3) ^ (row & 7));
      *(uint4*)&As[row * 64 + sslot * 8] =
          *(const uint4*)&A[(size_t)(m0 + row) * K_ + k0 + col];
      *(uint4*)&Bs[row * 64 + sslot * 8] =
          *(const uint4*)&Bt[(size_t)(n0 + row) * K_ + k0 + col];
    }
    __syncthreads();
#pragma unroll
    for (int kk = 0; kk < 2; ++kk) {
      bf16x8 a[4], b[4];
#pragma unroll
      for (int mi = 0; mi < 4; ++mi) {
        int row = wr * 64 + mi * 16 + lr;
        int slot = (kk * 4 + lg) ^ (row & 7);
        a[mi] = *(const bf16x8*)&As[row * 64 + slot * 8];
      }
#pragma unroll
      for (int ni = 0; ni < 4; ++ni) {
        int row = wc * 64 + ni * 16 + lr;
        int slot = (kk * 4 + lg) ^ (row & 7);
        b[ni] = *(const bf16x8*)&Bs[row * 64 + slot * 8];
      }
#pragma unroll
      for (int mi = 0; mi < 4; ++mi)
#pragma unroll
        for (int ni = 0; ni < 4; ++ni)
          acc[mi][ni] = __builtin_amdgcn_mfma_f32_16x16x32_bf16(a[mi], b[ni], acc[mi][ni], 0, 0, 0);
    }
    __syncthreads();
  }

  // epilogue: D layout col=lane&15, row=4*(lane>>4)+r
#pragma unroll
  for (int mi = 0; mi < 4; ++mi) {
    int rowb = m0 + wr * 64 + mi * 16 + lg * 4;
#pragma unroll
    for (int ni = 0; ni < 4; ++ni) {
      int col = n0 + wc * 64 + ni * 16 + lr;
      float bv = bias[col];
#pragma unroll
      for (int r = 0; r < 4; ++r) {
        size_t off = (size_t)(rowb + r) * N_ + col;
        float val = acc[mi][ni][r] + bv;
        if (OUTMODE == 0) ((ushort_t*)Cout)[off] = f2bf(val);
        else              ((float*)Cout)[off]   = val + res[off];
      }
    }
  }
}

// ---------------- RoPE in-place on q,k (bf16 pair per uint) ----------------
__global__ __launch_bounds__(256) void rope_kernel(unsigned* __restrict__ q,
                                                   unsigned* __restrict__ k,
                                                   const float* __restrict__ cosb,
                                                   const float* __restrict__ sinb) {
  int idx = blockIdx.x * 256 + threadIdx.x;  // = m*512 + p, p = h*32+i
  if (idx >= M_ * 512) return;
  int m = idx >> 9;
  int p = idx & 511;
  int l = m & 511;
  int i = p & 31;
  float c = cosb[l * 32 + i], s = sinb[l * 32 + i];
  {
    unsigned pk = q[idx];
    float x1 = bf2f((ushort_t)(pk & 0xffff)), x2 = bf2f((ushort_t)(pk >> 16));
    float y1 = x1 * c - x2 * s, y2 = x1 * s + x2 * c;
    q[idx] = (unsigned)f2bf(y1) | ((unsigned)f2bf(y2) << 16);
  }
  {
    unsigned pk = k[idx];
    float x1 = bf2f((ushort_t)(pk & 0xffff)), x2 = bf2f((ushort_t)(pk >> 16));
    float y1 = x1 * c - x2 * s, y2 = x1 * s + x2 * c;
    k[idx] = (unsigned)f2bf(y1) | ((unsigned)f2bf(y2) << 16);
  }
}

// ---------------- V transpose: vt[bh][hd][l] = v[b*512+l][h*64+hd] ----------------
__global__ __launch_bounds__(256) void vtrans_kernel(const ushort_t* __restrict__ v,
                                                     ushort_t* __restrict__ vt) {
  __shared__ ushort_t tile[64][72];
  int t = threadIdx.x;
  int bh = blockIdx.x >> 3, lt = blockIdx.x & 7;
  int b = bh >> 4, h = bh & 15;
  int l0 = lt * 64;
  for (int i = t; i < 64 * 64; i += 256) {
    int li = i >> 6, hd = i & 63;
    tile[li][hd] = v[(size_t)(b * 512 + l0 + li) * 1024 + h * 64 + hd];
  }
  __syncthreads();
  for (int i = t; i < 64 * 64; i += 256) {
    int hd = i >> 6, li = i & 63;
    vt[((size_t)bh * 64 + hd) * 512 + l0 + li] = tile[li][hd];
  }
}

// ---------------- Flash attention: 4 waves x 16 q-rows, KV tile 32 ----------------
__global__ __launch_bounds__(256) void attn_kernel(const ushort_t* __restrict__ q,
                                                   const ushort_t* __restrict__ k,
                                                   const ushort_t* __restrict__ vt,
                                                   ushort_t* __restrict__ o) {
  __shared__ ushort_t plds[4][16 * 32];
  int t = threadIdx.x, l = t & 63, w = t >> 6;
  int blk = blockIdx.x;
  int bh = blk >> 3, qt = blk & 7;
  int b = bh >> 4, h = bh & 15;
  int lr = l & 15, lg = l >> 4;

  int qrow = b * 512 + qt * 64 + w * 16 + lr;
  const ushort_t* qp = q + (size_t)qrow * 1024 + h * 64;
  bf16x8 aq0 = *(const bf16x8*)&qp[lg * 8];
  bf16x8 aq1 = *(const bf16x8*)&qp[32 + lg * 8];

  f32x4 oacc[4] = {};
  float mrun[4] = {-1e30f, -1e30f, -1e30f, -1e30f};
  float lrun[4] = {};
  const float scale = 0.125f;

  for (int kv0 = 0; kv0 < 512; kv0 += 32) {
    f32x4 s[2] = {};
#pragma unroll
    for (int n = 0; n < 2; ++n) {
      int krow = b * 512 + kv0 + n * 16 + lr;
      const ushort_t* kp = k + (size_t)krow * 1024 + h * 64;
      bf16x8 bk0 = *(const bf16x8*)&kp[lg * 8];
      bf16x8 bk1 = *(const bf16x8*)&kp[32 + lg * 8];
      s[n] = __builtin_amdgcn_mfma_f32_16x16x32_bf16(aq0, bk0, s[n], 0, 0, 0);
      s[n] = __builtin_amdgcn_mfma_f32_16x16x32_bf16(aq1, bk1, s[n], 0, 0, 0);
    }
    // online softmax (rows = 4*lg + r, cols across 16 lanes x 2 halves)
#pragma unroll
    for (int r = 0; r < 4; ++r) {
      s[0][r] *= scale; s[1][r] *= scale;
      float mx = fmaxf(s[0][r], s[1][r]);
#pragma unroll
      for (int msk = 1; msk < 16; msk <<= 1) mx = fmaxf(mx, __shfl_xor(mx, msk));
      float mn = fmaxf(mrun[r], mx);
      float al = __expf(mrun[r] - mn);
      mrun[r] = mn;
      float p0 = __expf(s[0][r] - mn);
      float p1 = __expf(s[1][r] - mn);
      s[0][r] = p0; s[1][r] = p1;
      float sm = p0 + p1;
#pragma unroll
      for (int msk = 1; msk < 16; msk <<= 1) sm += __shfl_xor(sm, msk);
      lrun[r] = lrun[r] * al + sm;
#pragma unroll
      for (int f = 0; f < 4; ++f) oacc[f][r] *= al;
    }
    // P -> bf16 -> per-wave LDS (swizzled 16B slots), then A-frag read
    ushort_t* pl = plds[w];
#pragma unroll
    for (int n = 0; n < 2; ++n)
#pragma unroll
      for (int r = 0; r < 4; ++r) {
        int rowp = lg * 4 + r;
        int c = n * 16 + lr;
        int sslot = ((c >> 3) ^ (rowp & 3));
        pl[rowp * 32 + sslot * 8 + (c & 7)] = f2bf(s[n][r]);
      }
    int rslot = (lg ^ (lr & 3));
    bf16x8 pa = *(const bf16x8*)&pl[lr * 32 + rslot * 8];
#pragma unroll
    for (int f = 0; f < 4; ++f) {
      const ushort_t* vp = vt + ((size_t)bh * 64 + f * 16 + lr) * 512 + kv0 + lg * 8;
      bf16x8 bv = *(const bf16x8*)vp;
      oacc[f] = __builtin_amdgcn_mfma_f32_16x16x32_bf16(pa, bv, oacc[f], 0, 0, 0);
    }
  }
  int om = b * 512 + qt * 64 + w * 16;
#pragma unroll
  for (int f = 0; f < 4; ++f)
#pragma unroll
    for (int r = 0; r < 4; ++r) {
      float val = oacc[f][r] / lrun[r];
      o[(size_t)(om + lg * 4 + r) * 1024 + h * 64 + f * 16 + lr] = f2bf(val);
    }
}

// ---------------- launch ----------------
extern "C" void kernel_launch(void* const* d_in, const int* in_sizes, int n_in,
                              void* d_out, int out_size, void* d_ws, size_t ws_size,
                              hipStream_t stream) {
  const float* input_ids = (const float*)d_in[0];
  const float* Wq = (const float*)d_in[1];
  const float* bq = (const float*)d_in[2];
  const float* Wk = (const float*)d_in[3];
  const float* bk = (const float*)d_in[4];
  const float* Wv = (const float*)d_in[5];
  const float* bv = (const float*)d_in[6];
  const float* Wo = (const float*)d_in[7];
  const float* bo = (const float*)d_in[8];
  const float* g_attn = (const float*)d_in[13];
  const float* b_attn = (const float*)d_in[14];
  float* out = (float*)d_out;

  char* ws = (char*)d_ws;
  const size_t MB = 1024 * 1024;
  ushort_t* wt = (ushort_t*)(ws);                 // 4 x 1M bf16 (8MB): Wq^T,Wk^T,Wv^T,Wo^T
  ushort_t* xn = (ushort_t*)(ws + 8 * MB);        // 8MB: LN output, later reused as attn O
  ushort_t* qb = (ushort_t*)(ws + 16 * MB);       // 8MB
  ushort_t* kb = (ushort_t*)(ws + 24 * MB);       // 8MB
  ushort_t* vb = (ushort_t*)(ws + 32 * MB);       // 8MB
  ushort_t* vt = (ushort_t*)(ws + 40 * MB);       // 8MB
  float* cosb  = (float*)(ws + 48 * MB);          // 64KB
  float* sinb  = (float*)(ws + 48 * MB + 64 * 1024);

  rope_table_kernel<<<64, 256, 0, stream>>>(cosb, sinb);
  ln_kernel<<<4096, 256, 0, stream>>>(input_ids, g_attn, b_attn, xn);
  wtrans_kernel<<<dim3(32, 32, 4), dim3(32, 8), 0, stream>>>(Wq, Wk, Wv, Wo, wt);
  gemm_bt<0><<<dim3(8, 32), 256, 0, stream>>>(xn, wt + 0 * MB, bq, nullptr, qb);
  gemm_bt<0><<<dim3(8, 32), 256, 0, stream>>>(xn, wt + 1 * MB, bk, nullptr, kb);
  gemm_bt<0><<<dim3(8, 32), 256, 0, stream>>>(xn, wt + 2 * MB, bv, nullptr, vb);
  rope_kernel<<<8192, 256, 0, stream>>>((unsigned*)qb, (unsigned*)kb, cosb, sinb);
  vtrans_kernel<<<1024, 256, 0, stream>>>(vb, vt);
  attn_kernel<<<1024, 256, 0, stream>>>(qb, kb, vt, xn);  // xn now holds O (bf16)
  gemm_bt<1><<<dim3(8, 32), 256, 0, stream>>>(xn, wt + 3 * MB, bo, input_ids, out);
}

// Round 2
// 120.841 us; speedup vs baseline: 1.5513x; 1.5513x over previous
//
#include <hip/hip_runtime.h>

typedef unsigned short ushort_t;
typedef short bf16x8 __attribute__((ext_vector_type(8)));
typedef float f32x4 __attribute__((ext_vector_type(4)));

#define B_ 8
#define L_ 512
#define D_ 1024
#define H_ 16
#define M_ 4096

__device__ __forceinline__ ushort_t f2bf(float f) {
  union { float f; unsigned u; } v; v.f = f;
  unsigned r = v.u + 0x7FFFu + ((v.u >> 16) & 1u);
  return (ushort_t)(r >> 16);
}
__device__ __forceinline__ float bf2f(ushort_t h) {
  union { unsigned u; float f; } v; v.u = ((unsigned)h) << 16;
  return v.f;
}

// global -> LDS direct (16B per lane, dest = wave-uniform base + lane*16)
__device__ __forceinline__ void gl_lds16(const ushort_t* g, ushort_t* s) {
  __builtin_amdgcn_global_load_lds((const __attribute__((address_space(1))) void*)(g),
                                   (__attribute__((address_space(3))) void*)(s), 16, 0, 0);
}

// ---------------- RoPE cos/sin table: [512][32] ----------------
__global__ __launch_bounds__(256) void rope_table_kernel(float* __restrict__ cosb,
                                                         float* __restrict__ sinb) {
  int idx = blockIdx.x * 256 + threadIdx.x;
  if (idx >= L_ * 32) return;
  int l = idx >> 5, i = idx & 31;
  float inv = powf(10000.0f, (-2.0f * (float)i) / 1024.0f);
  float ang = (float)l * inv;
  cosb[idx] = cosf(ang);
  sinb[idx] = sinf(ang);
}

// ---------------- LayerNorm (fp32 in -> bf16 out) ----------------
__global__ __launch_bounds__(256) void ln_kernel(const float* __restrict__ x,
                                                 const float* __restrict__ g,
                                                 const float* __restrict__ b,
                                                 ushort_t* __restrict__ xn) {
  int row = blockIdx.x, t = threadIdx.x;
  float4 v = ((const float4*)(x + (size_t)row * D_))[t];
  float s  = v.x + v.y + v.z + v.w;
  float s2 = v.x * v.x + v.y * v.y + v.z * v.z + v.w * v.w;
#pragma unroll
  for (int m = 1; m < 64; m <<= 1) { s += __shfl_xor(s, m); s2 += __shfl_xor(s2, m); }
  __shared__ float red[8];
  int w = t >> 6;
  if ((t & 63) == 0) { red[w] = s; red[4 + w] = s2; }
  __syncthreads();
  s  = red[0] + red[1] + red[2] + red[3];
  s2 = red[4] + red[5] + red[6] + red[7];
  float mean = s * (1.0f / D_);
  float var  = s2 * (1.0f / D_) - mean * mean;
  float rs   = rsqrtf(var + 1e-5f);
  float4 gg = ((const float4*)g)[t];
  float4 bb = ((const float4*)b)[t];
  unsigned long long pk =
      (unsigned long long)f2bf((v.x - mean) * rs * gg.x + bb.x)
    | ((unsigned long long)f2bf((v.y - mean) * rs * gg.y + bb.y) << 16)
    | ((unsigned long long)f2bf((v.z - mean) * rs * gg.z + bb.z) << 32)
    | ((unsigned long long)f2bf((v.w - mean) * rs * gg.w + bb.w) << 48);
  *(unsigned long long*)(xn + (size_t)row * D_ + t * 4) = pk;
}

// ---------------- Weight transpose + fp32->bf16: WT[n][k] = W[k][n] ----------------
__global__ __launch_bounds__(256) void wtrans_kernel(const float* __restrict__ w0,
                                                     const float* __restrict__ w1,
                                                     const float* __restrict__ w2,
                                                     const float* __restrict__ w3,
                                                     ushort_t* __restrict__ wt) {
  const float* W = (blockIdx.z == 0) ? w0 : (blockIdx.z == 1) ? w1
                 : (blockIdx.z == 2) ? w2 : w3;
  ushort_t* WT = wt + (size_t)blockIdx.z * 1024 * 1024;
  __shared__ float tile[32][33];
  int tx = threadIdx.x, ty = threadIdx.y;  // 32 x 8
  int k0 = blockIdx.y * 32, n0 = blockIdx.x * 32;
#pragma unroll
  for (int j = 0; j < 4; ++j)
    tile[ty + 8 * j][tx] = W[(size_t)(k0 + ty + 8 * j) * 1024 + n0 + tx];
  __syncthreads();
#pragma unroll
  for (int j = 0; j < 4; ++j)
    WT[(size_t)(n0 + ty + 8 * j) * 1024 + k0 + tx] = f2bf(tile[tx][ty + 8 * j]);
}

// ---------------- GEMM body: C[m][n] = sum_k A[m][k]*Bt[n][k] (+bias,+res) ----------------
// m97 structure: global_load_lds staging (pre-swizzled source, rule #21), BK=64.
// BN=128: 4 waves 2x2, MI=4.  BN=64: 4 waves 4x1, MI=2.
template <int OUTMODE, int BN>
__device__ __forceinline__ void gemm_body(const ushort_t* __restrict__ A,
                                          const ushort_t* __restrict__ Bt,
                                          const float* __restrict__ bias,
                                          const float* __restrict__ res,
                                          void* __restrict__ Cout,
                                          ushort_t* As, ushort_t* Bs,
                                          int m0, int n0) {
  int t = threadIdx.x, l = t & 63, w = t >> 6, lr = l & 15, lg = l >> 4;
  constexpr int MI = (BN == 128) ? 4 : 2;
  const int wr = (BN == 128) ? (w >> 1) : w;
  const int wc = (BN == 128) ? (w & 1) : 0;
  const int mrow0 = wr * (MI * 16);
  const int ncol0 = wc * 64;
  const int srow = l >> 3;
  const int scol = ((l & 7) ^ (srow & 7)) * 8;  // pre-swizzled source col

  f32x4 acc[MI][4] = {};

  for (int k0 = 0; k0 < 1024; k0 += 64) {
#pragma unroll
    for (int i = 0; i < 4; ++i)
      gl_lds16(&A[(size_t)(m0 + w * 32 + i * 8 + srow) * 1024 + k0 + scol],
               &As[(w * 32 + i * 8) * 64]);
#pragma unroll
    for (int i = 0; i < BN / 32; ++i)
      gl_lds16(&Bt[(size_t)(n0 + w * (BN / 4) + i * 8 + srow) * 1024 + k0 + scol],
               &Bs[(w * (BN / 4) + i * 8) * 64]);
    __syncthreads();
#pragma unroll
    for (int kk = 0; kk < 2; ++kk) {
      bf16x8 a[MI], b[4];
#pragma unroll
      for (int mi = 0; mi < MI; ++mi) {
        int row = mrow0 + mi * 16 + lr;
        a[mi] = *(const bf16x8*)&As[row * 64 + (((kk * 4 + lg) ^ (lr & 7)) << 3)];
      }
#pragma unroll
      for (int ni = 0; ni < 4; ++ni) {
        int row = ncol0 + ni * 16 + lr;
        b[ni] = *(const bf16x8*)&Bs[row * 64 + (((kk * 4 + lg) ^ (lr & 7)) << 3)];
      }
#pragma unroll
      for (int mi = 0; mi < MI; ++mi)
#pragma unroll
        for (int ni = 0; ni < 4; ++ni)
          acc[mi][ni] = __builtin_amdgcn_mfma_f32_16x16x32_bf16(a[mi], b[ni], acc[mi][ni], 0, 0, 0);
    }
    __syncthreads();
  }

#pragma unroll
  for (int mi = 0; mi < MI; ++mi) {
    int rowb = m0 + mrow0 + mi * 16 + lg * 4;
#pragma unroll
    for (int ni = 0; ni < 4; ++ni) {
      int col = n0 + ncol0 + ni * 16 + lr;
      float bv = bias[col];
#pragma unroll
      for (int r = 0; r < 4; ++r) {
        size_t off = (size_t)(rowb + r) * 1024 + col;
        float val = acc[mi][ni][r] + bv;
        if (OUTMODE == 0) ((ushort_t*)Cout)[off] = f2bf(val);
        else              ((float*)Cout)[off]   = val + res[off];
      }
    }
  }
}

__global__ __launch_bounds__(256) void gemm_qkv_kernel(const ushort_t* __restrict__ xn,
                                                       const ushort_t* __restrict__ wt,
                                                       const float* __restrict__ bq,
                                                       const float* __restrict__ bk,
                                                       const float* __restrict__ bv,
                                                       ushort_t* __restrict__ qkv) {
  __shared__ ushort_t As[128 * 64];
  __shared__ ushort_t Bs[128 * 64];
  int z = blockIdx.z;
  const ushort_t* Bt = wt + (size_t)z * 1024 * 1024;
  const float* bias = (z == 0) ? bq : (z == 1) ? bk : bv;
  ushort_t* out = qkv + (size_t)z * 4096 * 1024;
  gemm_body<0, 128>(xn, Bt, bias, nullptr, out, As, Bs, blockIdx.y * 128, blockIdx.x * 128);
}

__global__ __launch_bounds__(256) void gemm_o_kernel(const ushort_t* __restrict__ A,
                                                     const ushort_t* __restrict__ Bt,
                                                     const float* __restrict__ bias,
                                                     const float* __restrict__ res,
                                                     float* __restrict__ out) {
  __shared__ ushort_t As[128 * 64];
  __shared__ ushort_t Bs[64 * 64];
  gemm_body<1, 64>(A, Bt, bias, res, out, As, Bs, blockIdx.y * 128, blockIdx.x * 64);
}

// ---------------- RoPE in-place on q,k; fold 0.125 attn scale into q ----------------
__global__ __launch_bounds__(256) void rope_kernel(unsigned* __restrict__ q,
                                                   unsigned* __restrict__ k,
                                                   const float* __restrict__ cosb,
                                                   const float* __restrict__ sinb) {
  int idx = blockIdx.x * 256 + threadIdx.x;  // = m*512 + p, p = h*32+i
  if (idx >= M_ * 512) return;
  int m = idx >> 9;
  int p = idx & 511;
  int l = m & 511;
  int i = p & 31;
  float c = cosb[l * 32 + i], s = sinb[l * 32 + i];
  {
    unsigned pk = q[idx];
    float x1 = bf2f((ushort_t)(pk & 0xffff)), x2 = bf2f((ushort_t)(pk >> 16));
    float y1 = (x1 * c - x2 * s) * 0.125f, y2 = (x1 * s + x2 * c) * 0.125f;
    q[idx] = (unsigned)f2bf(y1) | ((unsigned)f2bf(y2) << 16);
  }
  {
    unsigned pk = k[idx];
    float x1 = bf2f((ushort_t)(pk & 0xffff)), x2 = bf2f((ushort_t)(pk >> 16));
    float y1 = x1 * c - x2 * s, y2 = x1 * s + x2 * c;
    k[idx] = (unsigned)f2bf(y1) | ((unsigned)f2bf(y2) << 16);
  }
}

// ---------------- V transpose: vt[bh*64+hd][l] = v[b*512+l][h*64+hd] ----------------
__global__ __launch_bounds__(256) void vtrans_kernel(const ushort_t* __restrict__ v,
                                                     ushort_t* __restrict__ vt) {
  __shared__ ushort_t tile[64][72];
  int t = threadIdx.x;
  int bh = blockIdx.x >> 3, lt = blockIdx.x & 7;
  int b = bh >> 4, h = bh & 15;
  int l0 = lt * 64;
  for (int i = t; i < 64 * 64; i += 256) {
    int li = i >> 6, hd = i & 63;
    tile[li][hd] = v[(size_t)(b * 512 + l0 + li) * 1024 + h * 64 + hd];
  }
  __syncthreads();
  for (int i = t; i < 64 * 64; i += 256) {
    int hd = i >> 6, li = i & 63;
    vt[((size_t)bh * 64 + hd) * 512 + l0 + li] = tile[li][hd];
  }
}

// ---------------- Flash attention, swapped-operand form ----------------
// Grid: blk = qt*128 + bh  (same bh -> same XCD). 4 waves x 32 q-rows = 128 q/block.
// K,Vt LDS-staged (gload_lds, dbuf, XOR-swizzled via pre-swizzled source).
// S^T = mfma(K,Q): lane-local softmax per q=lane&15. O^T = mfma(Vt,P).
__global__ __launch_bounds__(256) void attn_kernel(const ushort_t* __restrict__ q,
                                                   const ushort_t* __restrict__ k,
                                                   const ushort_t* __restrict__ vt,
                                                   ushort_t* __restrict__ o) {
  __shared__ ushort_t Ks[2][64 * 64];
  __shared__ ushort_t Vs[2][64 * 64];
  __shared__ ushort_t Ps[4][2][16 * 64];
  int t = threadIdx.x, l = t & 63, w = t >> 6, lr = l & 15, lg = l >> 4;
  int blk = blockIdx.x;
  int bh = blk & 127, qt = blk >> 7;
  int b = bh >> 4, h = bh & 15;
  const int srow = l >> 3;
  const int scol = ((l & 7) ^ (srow & 7)) * 8;

  // Q fragments in registers for the whole kernel (B-operand: col=q=lr, k=d)
  bf16x8 qf[2][2];
#pragma unroll
  for (int qm = 0; qm < 2; ++qm) {
    size_t qrow = (size_t)(b * 512 + qt * 128 + w * 32 + qm * 16 + lr);
#pragma unroll
    for (int kh = 0; kh < 2; ++kh)
      qf[qm][kh] = *(const bf16x8*)&q[qrow * 1024 + h * 64 + kh * 32 + lg * 8];
  }

  f32x4 oacc[2][4] = {};
  float mrun[2] = {-1e30f, -1e30f};
  float lrun[2] = {0.f, 0.f};

#define STAGE(buf, kv0)                                                              \
  {                                                                                  \
    _Pragma("unroll")                                                                \
    for (int j = 0; j < 2; ++j) {                                                    \
      gl_lds16(&k[(size_t)(b * 512 + (kv0) + w * 16 + j * 8 + srow) * 1024 + h * 64 + scol], \
               &Ks[buf][(w * 16 + j * 8) * 64]);                                     \
      gl_lds16(&vt[((size_t)bh * 64 + w * 16 + j * 8 + srow) * 512 + (kv0) + scol],  \
               &Vs[buf][(w * 16 + j * 8) * 64]);                                     \
    }                                                                                \
  }

  STAGE(0, 0);
  __syncthreads();
  int cur = 0;
  for (int it = 0; it < 8; ++it) {
    if (it < 7) { STAGE(cur ^ 1, (it + 1) * 64); }
    // QK^T swapped: st[qm][kn], kv = kn*16+4*lg+r, q = qm*16+lr
    f32x4 st[2][4] = {};
#pragma unroll
    for (int kh = 0; kh < 2; ++kh) {
#pragma unroll
      for (int kn = 0; kn < 4; ++kn) {
        bf16x8 kf = *(const bf16x8*)&Ks[cur][(kn * 16 + lr) * 64 + (((kh * 4 + lg) ^ (lr & 7)) << 3)];
        st[0][kn] = __builtin_amdgcn_mfma_f32_16x16x32_bf16(kf, qf[0][kh], st[0][kn], 0, 0, 0);
        st[1][kn] = __builtin_amdgcn_mfma_f32_16x16x32_bf16(kf, qf[1][kh], st[1][kn], 0, 0, 0);
      }
    }
    // lane-local online softmax (q = lr fixed per lane)
#pragma unroll
    for (int qm = 0; qm < 2; ++qm) {
      float mx = st[qm][0][0];
#pragma unroll
      for (int kn = 0; kn < 4; ++kn)
#pragma unroll
        for (int r = 0; r < 4; ++r) mx = fmaxf(mx, st[qm][kn][r]);
      mx = fmaxf(mx, __shfl_xor(mx, 16));
      mx = fmaxf(mx, __shfl_xor(mx, 32));
      float mn = fmaxf(mrun[qm], mx);
      float al = __expf(mrun[qm] - mn);
      mrun[qm] = mn;
      float sm = 0.f;
#pragma unroll
      for (int kn = 0; kn < 4; ++kn) {
#pragma unroll
        for (int r = 0; r < 4; ++r) {
          float p = __expf(st[qm][kn][r] - mn);
          sm += p;
          int kv = kn * 16 + 4 * lg + r;
          Ps[w][qm][lr * 64 + (((kv >> 3) ^ (lr & 7)) << 3) + (kv & 7)] = f2bf(p);
        }
      }
      sm += __shfl_xor(sm, 16);
      sm += __shfl_xor(sm, 32);
      lrun[qm] = lrun[qm] * al + sm;
#pragma unroll
      for (int f = 0; f < 4; ++f) {
        oacc[qm][f][0] *= al; oacc[qm][f][1] *= al;
        oacc[qm][f][2] *= al; oacc[qm][f][3] *= al;
      }
    }
    asm volatile("s_waitcnt lgkmcnt(0)" ::: "memory");
    __builtin_amdgcn_sched_barrier(0);
    // PV swapped: O^T[d][q] via mfma(A=Vt tile, B=P[q][kv])
#pragma unroll
    for (int kk = 0; kk < 2; ++kk) {
      bf16x8 pb0 = *(const bf16x8*)&Ps[w][0][lr * 64 + (((kk * 4 + lg) ^ (lr & 7)) << 3)];
      bf16x8 pb1 = *(const bf16x8*)&Ps[w][1][lr * 64 + (((kk * 4 + lg) ^ (lr & 7)) << 3)];
#pragma unroll
      for (int f = 0; f < 4; ++f) {
        bf16x8 vf = *(const bf16x8*)&Vs[cur][(f * 16 + lr) * 64 + (((kk * 4 + lg) ^ (lr & 7)) << 3)];
        oacc[0][f] = __builtin_amdgcn_mfma_f32_16x16x32_bf16(vf, pb0, oacc[0][f], 0, 0, 0);
        oacc[1][f] = __builtin_amdgcn_mfma_f32_16x16x32_bf16(vf, pb1, oacc[1][f], 0, 0, 0);
      }
    }
    __syncthreads();
    cur ^= 1;
  }
  // O^T: oacc[qm][f][r] = O[q = qm*16+lr][d = f*16+4*lg+r] -> pack 4 along d
#pragma unroll
  for (int qm = 0; qm < 2; ++qm) {
    float inv = 1.0f / lrun[qm];
    size_t qrow = (size_t)(b * 512 + qt * 128 + w * 32 + qm * 16 + lr);
#pragma unroll
    for (int f = 0; f < 4; ++f) {
      unsigned long long pk =
          (unsigned long long)f2bf(oacc[qm][f][0] * inv)
        | ((unsigned long long)f2bf(oacc[qm][f][1] * inv) << 16)
        | ((unsigned long long)f2bf(oacc[qm][f][2] * inv) << 32)
        | ((unsigned long long)f2bf(oacc[qm][f][3] * inv) << 48);
      *(unsigned long long*)&o[qrow * 1024 + h * 64 + f * 16 + 4 * lg] = pk;
    }
  }
#undef STAGE
}

// ---------------- launch ----------------
extern "C" void kernel_launch(void* const* d_in, const int* in_sizes, int n_in,
                              void* d_out, int out_size, void* d_ws, size_t ws_size,
                              hipStream_t stream) {
  const float* input_ids = (const float*)d_in[0];
  const float* Wq = (const float*)d_in[1];
  const float* bq = (const float*)d_in[2];
  const float* Wk = (const float*)d_in[3];
  const float* bk = (const float*)d_in[4];
  const float* Wv = (const float*)d_in[5];
  const float* bv = (const float*)d_in[6];
  const float* Wo = (const float*)d_in[7];
  const float* bo = (const float*)d_in[8];
  const float* g_attn = (const float*)d_in[13];
  const float* b_attn = (const float*)d_in[14];
  float* out = (float*)d_out;

  char* ws = (char*)d_ws;
  const size_t MB = 1024 * 1024;
  ushort_t* wt = (ushort_t*)(ws);                 // 4 x 1M bf16 (8MB)
  ushort_t* xn = (ushort_t*)(ws + 8 * MB);        // 8MB: LN out, later attn O
  ushort_t* qkv = (ushort_t*)(ws + 16 * MB);      // 24MB: q,k,v contiguous
  ushort_t* qb = qkv;
  ushort_t* kb = qkv + 4 * MB;
  ushort_t* vb = qkv + 8 * MB;
  ushort_t* vt = (ushort_t*)(ws + 40 * MB);       // 8MB
  float* cosb  = (float*)(ws + 48 * MB);          // 64KB
  float* sinb  = (float*)(ws + 48 * MB + 64 * 1024);

  rope_table_kernel<<<64, 256, 0, stream>>>(cosb, sinb);
  ln_kernel<<<4096, 256, 0, stream>>>(input_ids, g_attn, b_attn, xn);
  wtrans_kernel<<<dim3(32, 32, 4), dim3(32, 8), 0, stream>>>(Wq, Wk, Wv, Wo, wt);
  gemm_qkv_kernel<<<dim3(8, 32, 3), 256, 0, stream>>>(xn, wt, bq, bk, bv, qkv);
  rope_kernel<<<8192, 256, 0, stream>>>((unsigned*)qb, (unsigned*)kb, cosb, sinb);
  vtrans_kernel<<<1024, 256, 0, stream>>>(vb, vt);
  attn_kernel<<<512, 256, 0, stream>>>(qb, kb, vt, xn);  // xn <- O (bf16)
  gemm_o_kernel<<<dim3(16, 32), 256, 0, stream>>>(xn, wt + 3 * MB, bo, input_ids, out);
}